// Round 3
// baseline (227.382 us; speedup 1.0000x reference)
//
#include <hip/hip_runtime.h>
#include <hip/hip_bf16.h>
#include <stdint.h>

#define N_   64
#define L_   1024
#define D_   512
#define S_   127
#define OUT_ 300
#define NT_  20            // 20 col-tiles of 16 -> 320 padded cols
#define OUTP (NT_*16)      // 320
#define EPS_ 1e-5f
#define M_TOTAL (N_*S_)    // 8128

// small prep kernel block ranges
#define WBLK 640           // OUTP*D_/256  : w_lin f32 -> bf16 (padded 320 rows)
#define UBLK 32            // N_*D_/4/256  : use = t1[:,0,:]

// fused main kernel
#define BM   16
#define GBLK (M_TOTAL/BM)  // 508 (exact) -> 2 blocks/CU
#define ASTR 520           // LDS A row stride in bf16 (1040B: rows step 4 banks)
#define HSTR 320           // epilogue h stride (floats)

typedef __attribute__((ext_vector_type(4))) float  float4v;
typedef __attribute__((ext_vector_type(8))) __bf16 bf16x8;
typedef __attribute__((ext_vector_type(4))) __bf16 bf16x4;

// ---------------------------------------------------------------------------
// prep_small: (a) w_lin f32 -> bf16 padded to 320 rows, (b) use = t1[:,0,:].
// Tiny (~1.4 MB traffic) — must precede main kernel (wbf dependency).
// ---------------------------------------------------------------------------
__global__ __launch_bounds__(256) void prep_small(
    const float* __restrict__ t1, const float* __restrict__ w_lin,
    __bf16* __restrict__ wbf, float* __restrict__ use_out)
{
    const int blk = blockIdx.x;
    const int tid = threadIdx.x;
    if (blk < WBLK) {                       // --- w_lin -> bf16, pad rows>=300
        int idx = blk * 256 + tid;          // 320*512 threads
        int o = idx >> 9, d = idx & (D_ - 1);
        float v = (o < OUT_) ? w_lin[o * D_ + d] : 0.0f;
        wbf[idx] = (__bf16)v;
    } else {                                // --- use = t1[:,0,:]
        int idx = (blk - WBLK) * 256 + tid; // 8192 threads, float4 each
        int n = idx >> 7, dg = idx & 127;
        float4v v = *(const float4v*)(t1 + (size_t)n * L_ * D_ + dg * 4);
        *(float4v*)(use_out + n * D_ + dg * 4) = v;
    }
}

// ---------------------------------------------------------------------------
// enc_fused: span-means (staged ONCE to LDS) -> bf16 MFMA GEMM with B read
// directly from L2-resident weights (barrier-free K-loop) -> bias -> LN.
// BM=16 rows/block, 256 thr (4 waves x 5 col-tiles), 508 blocks = 2/CU.
// Exactly 2 __syncthreads() in the whole kernel.
// ---------------------------------------------------------------------------
__global__ __launch_bounds__(256) void enc_fused(
    const float* __restrict__ t1, const int* __restrict__ wseq,
    const __bf16* __restrict__ wbf, const float* __restrict__ b_lin,
    const float* __restrict__ gamma, const float* __restrict__ beta,
    float* __restrict__ out)
{
    __shared__ __align__(16) char smem[BM * HSTR * 4];   // 20480 B
    __bf16* Alds = (__bf16*)smem;      // [16][520] = 16640 B
    float*  hlds = (float*)smem;       // [16][320], aliased after K-loop barrier

    const int tid  = threadIdx.x;
    const int blk  = blockIdx.x;
    const int m0   = blk * BM;
    const int lane = tid & 63;
    const int wave = tid >> 6;         // 0..3 -> col tiles [wave*5, wave*5+5)
    const int quad = lane >> 4;
    const int ln16 = lane & 15;

    // ---- phase 1: span means for all 16 rows x 512 k, staged once.
    // 2048 tasks (row, float4-group); 8 per thread; lanes are k-contiguous
    // -> every wave-load is a contiguous 1 KiB segment of t1.
    #pragma unroll
    for (int it = 0; it < 8; ++it) {
        int idx = tid + it * 256;              // < 2048
        int row = idx >> 7, cg = idx & 127;
        int sp  = m0 + row;
        int nn  = sp / S_;
        int st  = min(wseq[sp * 2 + 0], L_ - 3);   // min(start, li-1)
        int en  = min(wseq[sp * 2 + 1], L_ - 2);   // min(end, li)
        int cnt = en - st;
        const float* base = t1 + ((size_t)nn * L_ + 1 + st) * D_ + cg * 4;
        float4v s4 = {0.f, 0.f, 0.f, 0.f};
        if (cnt == 8) {                        // fast path (always true here)
            #pragma unroll
            for (int j = 0; j < 8; ++j) s4 += *(const float4v*)(base + j * D_);
        } else {
            for (int j = 0; j < cnt; ++j)   s4 += *(const float4v*)(base + j * D_);
        }
        s4 *= 1.0f / (float)cnt;
        bf16x4 a4;
        a4[0] = (__bf16)s4[0]; a4[1] = (__bf16)s4[1];
        a4[2] = (__bf16)s4[2]; a4[3] = (__bf16)s4[3];
        *(bf16x4*)(Alds + row * ASTR + cg * 4) = a4;
    }
    __syncthreads();   // barrier #1 — A tile ready

    // ---- phase 2: barrier-free K-loop; B fragments straight from global
    // (320 KiB weight matrix is L2-resident on every XCD after 1st block).
    float4v acc[5];
    #pragma unroll
    for (int i = 0; i < 5; ++i) acc[i] = float4v{0.f, 0.f, 0.f, 0.f};

    const __bf16* bbase  = wbf + (size_t)(wave * 80 + ln16) * D_ + quad * 8;
    const __bf16* albase = Alds + ln16 * ASTR + quad * 8;

    #pragma unroll
    for (int kt = 0; kt < 8; ++kt) {
        #pragma unroll
        for (int ks = 0; ks < 2; ++ks) {
            const int kk = kt * 64 + ks * 32;
            bf16x8 af = *(const bf16x8*)(albase + kk);
            #pragma unroll
            for (int i = 0; i < 5; ++i) {
                bf16x8 bfr = *(const bf16x8*)(bbase + (size_t)i * 16 * D_ + kk);
                acc[i] = __builtin_amdgcn_mfma_f32_16x16x32_bf16(af, bfr, acc[i], 0, 0, 0);
            }
        }
    }
    __syncthreads();   // barrier #2 — all Alds reads done before h aliases LDS

    // ---- epilogue: h = acc + bias (C layout: row = quad*4+reg, col = ln16)
    #pragma unroll
    for (int i = 0; i < 5; ++i) {
        const int col = (wave * 5 + i) * 16 + ln16;
        const float bl = (col < OUT_) ? b_lin[col] : 0.0f;
        #pragma unroll
        for (int r = 0; r < 4; ++r)
            hlds[(quad * 4 + r) * HSTR + col] = acc[i][r] + bl;
    }
    __syncthreads();

    // ---- LayerNorm over 300 cols; 16 threads/row, shfl-reduce in 16-lane groups
    const int r  = tid >> 4;           // 0..15
    const int c0 = tid & 15;
    float sum = 0.f, sq = 0.f;
    #pragma unroll
    for (int i = 0; i < 19; ++i) {
        int c = c0 + 16 * i;
        if (c < OUT_) { float v = hlds[r * HSTR + c]; sum += v; sq += v * v; }
    }
    #pragma unroll
    for (int off = 8; off > 0; off >>= 1) {
        sum += __shfl_xor(sum, off);
        sq  += __shfl_xor(sq,  off);
    }
    const float mu  = sum * (1.0f / OUT_);
    const float var = sq * (1.0f / OUT_) - mu * mu;
    const float rs  = rsqrtf(var + EPS_);
    float* orow = out + (size_t)(m0 + r) * OUT_;
    #pragma unroll
    for (int i = 0; i < 19; ++i) {
        int c = c0 + 16 * i;
        if (c < OUT_) {
            float v = hlds[r * HSTR + c];
            orow[c] = (v - mu) * rs * gamma[c] + beta[c];
        }
    }
}

extern "C" void kernel_launch(void* const* d_in, const int* in_sizes, int n_in,
                              void* d_out, int out_size, void* d_ws, size_t ws_size,
                              hipStream_t stream) {
    const float* t1    = (const float*)d_in[0];
    const int*   wseq  = (const int*)d_in[1];   // word_seq (int32); d_in[2] mask unused
    const float* w_lin = (const float*)d_in[3];
    const float* b_lin = (const float*)d_in[4];
    const float* gamma = (const float*)d_in[5];
    const float* beta  = (const float*)d_in[6];
    float* out  = (float*)d_out;
    __bf16* wbf = (__bf16*)d_ws;                // 320*512*2 = 327680 B of scratch

    prep_small<<<WBLK + UBLK, 256, 0, stream>>>(t1, w_lin, wbf,
                                                out + (size_t)M_TOTAL * OUT_);
    enc_fused<<<GBLK, 256, 0, stream>>>(t1, wseq, wbf, b_lin, gamma, beta, out);
}